// Round 5
// baseline (33423.746 us; speedup 1.0000x reference)
//
#include <hip/hip_runtime.h>
#include <math.h>

#define B 512
#define S_IN 128
#define S_OUT 64
#define T_DEC 63

// ---- workspace layout (floats); fits the proven ws floor of 140.5 MB ----
#define O_H0   0
#define O_H1   524288
#define O_C    1048576
#define O_BAR  1572864                  // 4 floats reserved (barrier counter)
#define O_HS0  1572868                  // hs0: 128*512*512 = 33,554,432
#define O_P1   (O_HS0 + 33554432)      // 35,127,300 floats = 140.509 MB

// ===========================================================================
// Encoder step (256 thr, 64x64 tile, 4x4 micro) — round-2 validated, verbatim.
// ===========================================================================
template<int MODE>
__global__ __launch_bounds__(256)
void enc_step(const float* __restrict__ Wih, const float* __restrict__ Whh,
              const float* __restrict__ bias, const int* __restrict__ tok,
              const float* __restrict__ emb, const float* __restrict__ seqin,
              const float* __restrict__ h_in, float* __restrict__ h_out,
              float* __restrict__ c_st, float* __restrict__ seqout,
              const float* __restrict__ p1, int t)
{
    constexpr int KE = (MODE==0) ? 64 : (MODE==2 ? 512 : 0);
    constexpr int K  = KE + 256;
    constexpr int NK = K/16;

    const int dir   = blockIdx.z;
    const int t_eff = dir ? (S_IN-1-t) : t;
    const int hseg  = (MODE==0) ? dir*256 : 512 + dir*256;

    const float* Wih_d = Wih + (size_t)dir*1024*KE;
    const float* Whh_d = Whh + (size_t)dir*1024*256;
    const float* b_d   = bias + dir*1024;

    __shared__ float As[16][64];
    __shared__ float Bs[16][64];

    const int tid = threadIdx.x;
    const int bm0 = blockIdx.x*64;
    const int bn0 = blockIdx.y*64;

    const int la_m  = tid >> 2;
    const int la_k  = (tid & 3) << 2;
    const int a_row = bm0 + la_m;

    const int lb_n = tid >> 2;
    const int lb_k = (tid & 3) << 2;
    const int n_g  = bn0 + lb_n;
    const int b_j  = (n_g & 3)*256 + (n_g >> 2);

    int tokidx = 0;
    if (MODE==0) tokidx = tok[t_eff*B + a_row];

    const int tm = (tid >> 4) << 2;
    const int tn = (tid & 15) << 2;

    float acc[4][4] = {};

    auto loadA = [&](int kt) -> float4 {
        int k = kt*16 + la_k;
        if (MODE==0) {
            if (k < 64) return *(const float4*)&emb[(size_t)tokidx*64 + k];
            return *(const float4*)&h_in[(size_t)a_row*1024 + hseg + (k-64)];
        } else if (MODE==2) {
            if (k < 512) return *(const float4*)&seqin[((size_t)t_eff*B + a_row)*512 + k];
            return *(const float4*)&h_in[(size_t)a_row*1024 + hseg + (k-512)];
        } else {
            return *(const float4*)&h_in[(size_t)a_row*1024 + hseg + k];
        }
    };
    auto loadB = [&](int kt) -> float4 {
        int k = kt*16 + lb_k;
        if (KE && k < KE) return *(const float4*)&Wih_d[(size_t)b_j*KE + k];
        return *(const float4*)&Whh_d[(size_t)b_j*256 + (k-KE)];
    };

    float4 aR = loadA(0), bR = loadB(0);
    for (int kt=0; kt<NK; ++kt) {
        __syncthreads();
        As[la_k+0][la_m]=aR.x; As[la_k+1][la_m]=aR.y; As[la_k+2][la_m]=aR.z; As[la_k+3][la_m]=aR.w;
        Bs[lb_k+0][lb_n]=bR.x; Bs[lb_k+1][lb_n]=bR.y; Bs[lb_k+2][lb_n]=bR.z; Bs[lb_k+3][lb_n]=bR.w;
        __syncthreads();
        if (kt+1 < NK) { aR = loadA(kt+1); bR = loadB(kt+1); }
        #pragma unroll
        for (int k=0;k<16;k++){
            const float4 a = *(const float4*)&As[k][tm];
            const float4 b = *(const float4*)&Bs[k][tn];
            acc[0][0]+=a.x*b.x; acc[0][1]+=a.x*b.y; acc[0][2]+=a.x*b.z; acc[0][3]+=a.x*b.w;
            acc[1][0]+=a.y*b.x; acc[1][1]+=a.y*b.y; acc[1][2]+=a.y*b.z; acc[1][3]+=a.y*b.w;
            acc[2][0]+=a.z*b.x; acc[2][1]+=a.z*b.y; acc[2][2]+=a.z*b.z; acc[2][3]+=a.z*b.w;
            acc[3][0]+=a.w*b.x; acc[3][1]+=a.w*b.y; acc[3][2]+=a.w*b.z; acc[3][3]+=a.w*b.w;
        }
    }

    const int jh = (bn0 + tn) >> 2;
    const float bi = b_d[0*256 + jh];
    const float bf = b_d[1*256 + jh];
    const float bg = b_d[2*256 + jh];
    const float bo = b_d[3*256 + jh];
    #pragma unroll
    for (int i=0;i<4;i++){
        const int brow = bm0 + tm + i;
        float xi = acc[i][0] + bi;
        float xf = acc[i][1] + bf;
        float xg = acc[i][2] + bg;
        float xo = acc[i][3] + bo;
        if (MODE==1) {
            const float4 pv = *(const float4*)&p1[((size_t)dir*512 + brow)*1024 + bn0 + tn];
            xi += pv.x; xf += pv.y; xg += pv.z; xo += pv.w;
        }
        float ig = 1.f/(1.f+expf(-xi));
        float fg = 1.f/(1.f+expf(-xf));
        float gg = tanhf(xg);
        float og = 1.f/(1.f+expf(-xo));
        size_t ci = (size_t)brow*1024 + hseg + jh;
        float cn = fg*c_st[ci] + ig*gg;
        float hn = og*tanhf(cn);
        c_st[ci]  = cn;
        h_out[ci] = hn;
        if (MODE==0) seqout[((size_t)t_eff*B + brow)*512 + dir*256 + jh] = hn;
    }
}

// ===========================================================================
// P1 precompute GEMM (round-2 validated, verbatim).
// ===========================================================================
__global__ __launch_bounds__(128)
void gemm_p1(const float* __restrict__ Wih, const float* __restrict__ hs0,
             float* __restrict__ p1out, int s0)
{
    constexpr int NK = 512/16;
    const int dir = blockIdx.z;

    __shared__ float As[16][64];
    __shared__ float Bs[16][64];

    const int tid = threadIdx.x;
    const int bm0 = blockIdx.x*64;
    const int bn0 = blockIdx.y*64;

    const int la_m  = tid >> 1;
    const int la_k  = (tid & 1) << 3;
    const int a_row = bm0 + la_m;

    const int srel  = blockIdx.x >> 3;
    const int sabs  = s0 + srel;
    const int t_eff = dir ? (S_IN-1-sabs) : sabs;
    const int a_b   = a_row & 511;

    const int n_g = bn0 + la_m;
    const int b_j = (n_g & 3)*256 + (n_g >> 2);

    const float* Wih_d = Wih + (size_t)dir*1024*512;

    const int tm = (tid >> 3) << 2;
    const int tn = (tid & 7) << 3;

    float acc[4][8] = {};

    auto loadA = [&](int kt, int q) -> float4 {
        int k = kt*16 + la_k + q*4;
        return *(const float4*)&hs0[((size_t)t_eff*B + a_b)*512 + k];
    };
    auto loadB = [&](int kt, int q) -> float4 {
        int k = kt*16 + la_k + q*4;
        return *(const float4*)&Wih_d[(size_t)b_j*512 + k];
    };

    float4 aR0 = loadA(0,0), aR1 = loadA(0,1);
    float4 bR0 = loadB(0,0), bR1 = loadB(0,1);
    for (int kt=0; kt<NK; ++kt) {
        __syncthreads();
        As[la_k+0][la_m]=aR0.x; As[la_k+1][la_m]=aR0.y; As[la_k+2][la_m]=aR0.z; As[la_k+3][la_m]=aR0.w;
        As[la_k+4][la_m]=aR1.x; As[la_k+5][la_m]=aR1.y; As[la_k+6][la_m]=aR1.z; As[la_k+7][la_m]=aR1.w;
        Bs[la_k+0][la_m]=bR0.x; Bs[la_k+1][la_m]=bR0.y; Bs[la_k+2][la_m]=bR0.z; Bs[la_k+3][la_m]=bR0.w;
        Bs[la_k+4][la_m]=bR1.x; Bs[la_k+5][la_m]=bR1.y; Bs[la_k+6][la_m]=bR1.z; Bs[la_k+7][la_m]=bR1.w;
        __syncthreads();
        if (kt+1 < NK) {
            aR0 = loadA(kt+1,0); aR1 = loadA(kt+1,1);
            bR0 = loadB(kt+1,0); bR1 = loadB(kt+1,1);
        }
        #pragma unroll
        for (int k=0;k<16;k++){
            const float4 a  = *(const float4*)&As[k][tm];
            const float4 b0 = *(const float4*)&Bs[k][tn];
            const float4 b1 = *(const float4*)&Bs[k][tn+4];
            acc[0][0]+=a.x*b0.x; acc[0][1]+=a.x*b0.y; acc[0][2]+=a.x*b0.z; acc[0][3]+=a.x*b0.w;
            acc[0][4]+=a.x*b1.x; acc[0][5]+=a.x*b1.y; acc[0][6]+=a.x*b1.z; acc[0][7]+=a.x*b1.w;
            acc[1][0]+=a.y*b0.x; acc[1][1]+=a.y*b0.y; acc[1][2]+=a.y*b0.z; acc[1][3]+=a.y*b0.w;
            acc[1][4]+=a.y*b1.x; acc[1][5]+=a.y*b1.y; acc[1][6]+=a.y*b1.z; acc[1][7]+=a.y*b1.w;
            acc[2][0]+=a.z*b0.x; acc[2][1]+=a.z*b0.y; acc[2][2]+=a.z*b0.z; acc[2][3]+=a.z*b0.w;
            acc[2][4]+=a.z*b1.x; acc[2][5]+=a.z*b1.y; acc[2][6]+=a.z*b1.z; acc[2][7]+=a.z*b1.w;
            acc[3][0]+=a.w*b0.x; acc[3][1]+=a.w*b0.y; acc[3][2]+=a.w*b0.z; acc[3][3]+=a.w*b0.w;
            acc[3][4]+=a.w*b1.x; acc[3][5]+=a.w*b1.y; acc[3][6]+=a.w*b1.z; acc[3][7]+=a.w*b1.w;
        }
    }

    #pragma unroll
    for (int i=0;i<4;i++){
        const int r = bm0 + tm + i;
        size_t base = ((size_t)(srel*2 + dir)*512 + (r & 511))*1024 + bn0 + tn;
        *(float4*)&p1out[base]   = *(float4*)&acc[i][0];
        *(float4*)&p1out[base+4] = *(float4*)&acc[i][4];
    }
}

// ===========================================================================
// Manual grid barrier (round-4 validated, verbatim).
// ===========================================================================
__device__ __forceinline__ void grid_bar(unsigned* cnt, unsigned target)
{
    __syncthreads();
    if (threadIdx.x == 0) {
        __threadfence();
        atomicAdd(cnt, 1u);
        while (__hip_atomic_load(cnt, __ATOMIC_ACQUIRE, __HIP_MEMORY_SCOPE_AGENT) < target) {
            __builtin_amdgcn_s_sleep(2);
        }
        __threadfence();
    }
    __syncthreads();
}

// ===========================================================================
// Persistent decoder, W-in-LDS. 256 blocks (1/CU) x 256 thr.
// Block owns 16 gate-cols (4 hidden units): W slice 16x1088 f32 = 69.6 KB
// pinned in LDS for all 63 steps (immune to fence L2-invalidation).
// A (emb||h, 512x1088) streamed per step through a 16-k LDS slice.
// Micro: (4+4)m x 4n; W-read wave-uniform (broadcast), A-read dense float4.
// Proj (round-4 validated math): rows 2b,2b+1. 2 grid barriers per step.
// ===========================================================================
#define FMA4(ac, s, w) { ac[0]+=(s)*(w).x; ac[1]+=(s)*(w).y; ac[2]+=(s)*(w).z; ac[3]+=(s)*(w).w; }

__global__ __launch_bounds__(256)
void dec_persist(const float* __restrict__ Wih, const float* __restrict__ Whh,
                 const float* __restrict__ bias, const int* __restrict__ tok,
                 const float* __restrict__ emb, const float* __restrict__ pW,
                 const float* __restrict__ pb, float* __restrict__ h0b,
                 float* __restrict__ h1b, float* __restrict__ c_st,
                 unsigned* __restrict__ bar, float* __restrict__ dout)
{
    extern __shared__ float smem[];
    float* Ws = smem;              // [1088][16]  69632 B
    float* As = smem + 17408;      // [16][512]   32768 B
    float* cs = smem + 25600;      // [2][1024]    8192 B
    float* ls = smem + 27648;      // [2][128]      512 B

    const int b = blockIdx.x, tid = threadIdx.x;
    const int bn0 = b*16;

    // ---- one-time W preload into LDS (gate-interleaved gather) ----
    {
        const int col = tid >> 4;
        const int n_g = bn0 + col;
        const int wrow = (n_g & 3)*1024 + (n_g >> 2);
        for (int k0 = (tid & 15)*4; k0 < 1088; k0 += 64) {
            float4 v;
            if (k0 < 64) v = *(const float4*)&Wih[(size_t)wrow*64 + k0];
            else         v = *(const float4*)&Whh[(size_t)wrow*1024 + (k0-64)];
            Ws[(k0+0)*16 + col] = v.x;
            Ws[(k0+1)*16 + col] = v.y;
            Ws[(k0+2)*16 + col] = v.z;
            Ws[(k0+3)*16 + col] = v.w;
        }
    }
    __syncthreads();

    const int m0  = (tid & 63)*4;          // 64 m-chunks of 4 rows
    const int tn  = (tid >> 6)*4;          // wave-uniform n-group (4 gates)
    const int jh  = (bn0 + tn) >> 2;       // hidden unit of this quad
    const float bi = bias[jh], bf = bias[1024+jh], bg_ = bias[2048+jh], bo = bias[3072+jh];
    const int r0 = tid, r1 = tid + 256;    // staging rows
    const int pr = tid >> 7, pc = tid & 127;  // proj mapping

    for (int t = 0; t < T_DEC; ++t) {
        const float* h_in  = (t & 1) ? h1b : h0b;
        float*       h_out = (t & 1) ? h0b : h1b;
        const int tok0 = tok[r0*S_OUT + t];
        const int tok1 = tok[r1*S_OUT + t];

        auto ldrow = [&](int r, int tk, int k) -> float4 {
            if (k < 64) return *(const float4*)&emb[(size_t)tk*64 + k];
            return *(const float4*)&h_in[(size_t)r*1024 + (k-64)];
        };

        float4 pre[8];
        #pragma unroll
        for (int j=0;j<4;j++){ pre[j] = ldrow(r0,tok0,j*4); pre[4+j] = ldrow(r1,tok1,j*4); }

        float acc0[4][4] = {}, acc1[4][4] = {};

        for (int kt = 0; kt < 68; ++kt) {
            __syncthreads();
            #pragma unroll
            for (int j=0;j<4;j++){
                As[(j*4+0)*512 + r0] = pre[j].x;
                As[(j*4+1)*512 + r0] = pre[j].y;
                As[(j*4+2)*512 + r0] = pre[j].z;
                As[(j*4+3)*512 + r0] = pre[j].w;
                As[(j*4+0)*512 + r1] = pre[4+j].x;
                As[(j*4+1)*512 + r1] = pre[4+j].y;
                As[(j*4+2)*512 + r1] = pre[4+j].z;
                As[(j*4+3)*512 + r1] = pre[4+j].w;
            }
            __syncthreads();
            if (kt+1 < 68) {
                const int kb = (kt+1)*16;
                #pragma unroll
                for (int j=0;j<4;j++){ pre[j] = ldrow(r0,tok0,kb+j*4); pre[4+j] = ldrow(r1,tok1,kb+j*4); }
            }
            const int kg = kt*16;
            #pragma unroll
            for (int kk=0;kk<16;kk++){
                const float4 w  = *(const float4*)&Ws[(kg+kk)*16 + tn];
                const float4 a0 = *(const float4*)&As[kk*512 + m0];
                const float4 a1 = *(const float4*)&As[kk*512 + m0 + 256];
                FMA4(acc0[0], a0.x, w); FMA4(acc0[1], a0.y, w);
                FMA4(acc0[2], a0.z, w); FMA4(acc0[3], a0.w, w);
                FMA4(acc1[0], a1.x, w); FMA4(acc1[1], a1.y, w);
                FMA4(acc1[2], a1.z, w); FMA4(acc1[3], a1.w, w);
            }
        }

        // ---- LSTM epilogue: 8 rows x 1 hidden unit ----
        #pragma unroll
        for (int i=0;i<4;i++){
            {
                const int row = m0 + i;
                float xi=acc0[i][0]+bi, xf=acc0[i][1]+bf, xg=acc0[i][2]+bg_, xo=acc0[i][3]+bo;
                float ig=1.f/(1.f+expf(-xi)), fg=1.f/(1.f+expf(-xf));
                float gg=tanhf(xg), og=1.f/(1.f+expf(-xo));
                const size_t ci=(size_t)row*1024 + jh;
                const float cn=fg*c_st[ci]+ig*gg, hn=og*tanhf(cn);
                c_st[ci]=cn; h_out[ci]=hn;
            }
            {
                const int row = m0 + 256 + i;
                float xi=acc1[i][0]+bi, xf=acc1[i][1]+bf, xg=acc1[i][2]+bg_, xo=acc1[i][3]+bo;
                float ig=1.f/(1.f+expf(-xi)), fg=1.f/(1.f+expf(-xf));
                float gg=tanhf(xg), og=1.f/(1.f+expf(-xo));
                const size_t ci=(size_t)row*1024 + jh;
                const float cn=fg*c_st[ci]+ig*gg, hn=og*tanhf(cn);
                c_st[ci]=cn; h_out[ci]=hn;
            }
        }

        grid_bar(bar, (unsigned)(2*t+1) * 256u);

        // ---- fused projection on cell state, rows 2b, 2b+1 (round-4 math) ----
        *(float4*)&cs[pr*1024 + pc*8]     = *(const float4*)&c_st[(size_t)(2*b+pr)*1024 + pc*8];
        *(float4*)&cs[pr*1024 + pc*8 + 4] = *(const float4*)&c_st[(size_t)(2*b+pr)*1024 + pc*8 + 4];
        __syncthreads();
        {
            float a0 = 0.f;
            for (int k=0;k<1024;k+=4){
                const float4 w  = *(const float4*)&pW[(size_t)pc*1024 + k];
                const float4 c0 = *(const float4*)&cs[pr*1024 + k];
                a0 += w.x*c0.x + w.y*c0.y + w.z*c0.z + w.w*c0.w;
            }
            ls[pr*128 + pc] = a0 + pb[pc];
        }
        __syncthreads();
        if (tid < 128) {
            const int r = tid >> 6, lane = tid & 63;
            const int gb = 2*b + r;
            const float v0 = ls[r*128 + lane], v1 = ls[r*128 + lane + 64];
            float mv; int mi;
            if (v1 > v0){ mv=v1; mi=lane+64; } else { mv=v0; mi=lane; }
            #pragma unroll
            for (int o=32;o>=1;o>>=1){
                const float ov = __shfl_xor(mv, o);
                const int   oi = __shfl_xor(mi, o);
                if (ov > mv || (ov == mv && oi < mi)){ mv=ov; mi=oi; }
            }
            float e = expf(v0-mv) + expf(v1-mv);
            #pragma unroll
            for (int o=32;o>=1;o>>=1) e += __shfl_xor(e, o);
            if (lane == 0){
                const int tnx = tok[gb*S_OUT + t + 1];
                const float logp = ls[r*128 + tnx] - mv - logf(e);
                const float cn = ((t==0)?0.f:dout[T_DEC*B + gb]) + logp;
                dout[T_DEC*B + gb] = cn;
                dout[t*B + gb] = (float)mi;
            }
        }

        grid_bar(bar, (unsigned)(2*t+2) * 256u);
    }
}

__global__ void zero_kernel(float* __restrict__ p, int n4){
    int i = blockIdx.x*blockDim.x + threadIdx.x;
    if (i < n4) *(float4*)&p[i*4] = float4{0.f,0.f,0.f,0.f};
}

extern "C" void kernel_launch(void* const* d_in, const int* in_sizes, int n_in,
                              void* d_out, int out_size, void* d_ws, size_t ws_size,
                              hipStream_t stream)
{
    const int*   input_tokens  = (const int*)d_in[0];
    const int*   output_tokens = (const int*)d_in[1];
    const float* in_emb  = (const float*)d_in[2];
    const float* eWih0   = (const float*)d_in[3];
    const float* eWhh0   = (const float*)d_in[4];
    const float* eb0     = (const float*)d_in[5];
    const float* eWih1   = (const float*)d_in[6];
    const float* eWhh1   = (const float*)d_in[7];
    const float* eb1     = (const float*)d_in[8];
    const float* out_emb = (const float*)d_in[9];
    const float* dWih    = (const float*)d_in[10];
    const float* dWhh    = (const float*)d_in[11];
    const float* db      = (const float*)d_in[12];
    const float* pW      = (const float*)d_in[13];
    const float* pb      = (const float*)d_in[14];

    size_t ws_fl = ws_size / 4;
    if (ws_fl < (size_t)O_P1) return;

    int CH = 0;
    if      (ws_fl >= (size_t)O_P1 + 16u*1048576u) CH = 16;
    else if (ws_fl >= (size_t)O_P1 +  8u*1048576u) CH = 8;
    else if (ws_fl >= (size_t)O_P1 +  4u*1048576u) CH = 4;
    else if (ws_fl >= (size_t)O_P1 +  2u*1048576u) CH = 2;

    float* ws   = (float*)d_ws;
    float* dout = (float*)d_out;

    float* h[2]   = { ws + O_H0, ws + O_H1 };
    float* c      = ws + O_C;
    unsigned* bar = (unsigned*)(ws + O_BAR);
    float* hs0    = ws + O_HS0;
    float* p1     = ws + O_P1;

    // zero h0,h1,c,bar
    zero_kernel<<<(O_HS0/4 + 255)/256, 256, 0, stream>>>(ws, O_HS0/4);

    // ---- encoder layer 0 (round-2 validated path) ----
    for (int t=0;t<S_IN;t++)
        enc_step<0><<<dim3(8,16,2),256,0,stream>>>(eWih0, eWhh0, eb0,
            input_tokens, in_emb, nullptr, h[t&1], h[(t+1)&1], c, hs0, nullptr, t);

    // ---- encoder layer 1 (round-2 validated path) ----
    if (CH) {
        for (int s0=0; s0<S_IN; s0+=CH) {
            gemm_p1<<<dim3(CH*8,16,2),128,0,stream>>>(eWih1, hs0, p1, s0);
            for (int s=s0; s<s0+CH; ++s)
                enc_step<1><<<dim3(8,16,2),256,0,stream>>>(eWih1, eWhh1, eb1,
                    nullptr, nullptr, nullptr, h[s&1], h[(s+1)&1], c, nullptr,
                    p1 + (size_t)(s-s0)*2*512*1024, s);
        }
    } else {
        for (int t=0;t<S_IN;t++)
            enc_step<2><<<dim3(8,16,2),256,0,stream>>>(eWih1, eWhh1, eb1,
                nullptr, nullptr, hs0, h[t&1], h[(t+1)&1], c, nullptr, nullptr, t);
    }

    // ---- persistent decoder: W pinned in LDS, 111,616 B dynamic ----
    dec_persist<<<256, 256, 111616, stream>>>(dWih, dWhh, db, output_tokens,
                                              out_emb, pW, pb, h[0], h[1], c,
                                              bar, dout);
}

// Round 7
// 23273.199 us; speedup vs baseline: 1.4361x; 1.4361x over previous
//
#include <hip/hip_runtime.h>
#include <math.h>

#define B 512
#define S_IN 128
#define S_OUT 64
#define T_DEC 63

// ---- workspace layout (floats); fits the proven ws floor of 140.5 MB ----
#define O_H0   0
#define O_H1   524288
#define O_C    1048576
#define O_BAR  1572864                  // 4 floats reserved (barrier counter)
#define O_HS0  1572868                  // hs0: 128*512*512 = 33,554,432
#define O_P1   (O_HS0 + 33554432)      // 35,127,300 floats = 140.509 MB

// ===========================================================================
// Encoder step (256 thr, 64x64 tile, 4x4 micro) — round-2 validated, verbatim.
// ===========================================================================
template<int MODE>
__global__ __launch_bounds__(256)
void enc_step(const float* __restrict__ Wih, const float* __restrict__ Whh,
              const float* __restrict__ bias, const int* __restrict__ tok,
              const float* __restrict__ emb, const float* __restrict__ seqin,
              const float* __restrict__ h_in, float* __restrict__ h_out,
              float* __restrict__ c_st, float* __restrict__ seqout,
              const float* __restrict__ p1, int t)
{
    constexpr int KE = (MODE==0) ? 64 : (MODE==2 ? 512 : 0);
    constexpr int K  = KE + 256;
    constexpr int NK = K/16;

    const int dir   = blockIdx.z;
    const int t_eff = dir ? (S_IN-1-t) : t;
    const int hseg  = (MODE==0) ? dir*256 : 512 + dir*256;

    const float* Wih_d = Wih + (size_t)dir*1024*KE;
    const float* Whh_d = Whh + (size_t)dir*1024*256;
    const float* b_d   = bias + dir*1024;

    __shared__ float As[16][64];
    __shared__ float Bs[16][64];

    const int tid = threadIdx.x;
    const int bm0 = blockIdx.x*64;
    const int bn0 = blockIdx.y*64;

    const int la_m  = tid >> 2;
    const int la_k  = (tid & 3) << 2;
    const int a_row = bm0 + la_m;

    const int lb_n = tid >> 2;
    const int lb_k = (tid & 3) << 2;
    const int n_g  = bn0 + lb_n;
    const int b_j  = (n_g & 3)*256 + (n_g >> 2);

    int tokidx = 0;
    if (MODE==0) tokidx = tok[t_eff*B + a_row];

    const int tm = (tid >> 4) << 2;
    const int tn = (tid & 15) << 2;

    float acc[4][4] = {};

    auto loadA = [&](int kt) -> float4 {
        int k = kt*16 + la_k;
        if (MODE==0) {
            if (k < 64) return *(const float4*)&emb[(size_t)tokidx*64 + k];
            return *(const float4*)&h_in[(size_t)a_row*1024 + hseg + (k-64)];
        } else if (MODE==2) {
            if (k < 512) return *(const float4*)&seqin[((size_t)t_eff*B + a_row)*512 + k];
            return *(const float4*)&h_in[(size_t)a_row*1024 + hseg + (k-512)];
        } else {
            return *(const float4*)&h_in[(size_t)a_row*1024 + hseg + k];
        }
    };
    auto loadB = [&](int kt) -> float4 {
        int k = kt*16 + lb_k;
        if (KE && k < KE) return *(const float4*)&Wih_d[(size_t)b_j*KE + k];
        return *(const float4*)&Whh_d[(size_t)b_j*256 + (k-KE)];
    };

    float4 aR = loadA(0), bR = loadB(0);
    for (int kt=0; kt<NK; ++kt) {
        __syncthreads();
        As[la_k+0][la_m]=aR.x; As[la_k+1][la_m]=aR.y; As[la_k+2][la_m]=aR.z; As[la_k+3][la_m]=aR.w;
        Bs[lb_k+0][lb_n]=bR.x; Bs[lb_k+1][lb_n]=bR.y; Bs[lb_k+2][lb_n]=bR.z; Bs[lb_k+3][lb_n]=bR.w;
        __syncthreads();
        if (kt+1 < NK) { aR = loadA(kt+1); bR = loadB(kt+1); }
        #pragma unroll
        for (int k=0;k<16;k++){
            const float4 a = *(const float4*)&As[k][tm];
            const float4 b = *(const float4*)&Bs[k][tn];
            acc[0][0]+=a.x*b.x; acc[0][1]+=a.x*b.y; acc[0][2]+=a.x*b.z; acc[0][3]+=a.x*b.w;
            acc[1][0]+=a.y*b.x; acc[1][1]+=a.y*b.y; acc[1][2]+=a.y*b.z; acc[1][3]+=a.y*b.w;
            acc[2][0]+=a.z*b.x; acc[2][1]+=a.z*b.y; acc[2][2]+=a.z*b.z; acc[2][3]+=a.z*b.w;
            acc[3][0]+=a.w*b.x; acc[3][1]+=a.w*b.y; acc[3][2]+=a.w*b.z; acc[3][3]+=a.w*b.w;
        }
    }

    const int jh = (bn0 + tn) >> 2;
    const float bi = b_d[0*256 + jh];
    const float bf = b_d[1*256 + jh];
    const float bg = b_d[2*256 + jh];
    const float bo = b_d[3*256 + jh];
    #pragma unroll
    for (int i=0;i<4;i++){
        const int brow = bm0 + tm + i;
        float xi = acc[i][0] + bi;
        float xf = acc[i][1] + bf;
        float xg = acc[i][2] + bg;
        float xo = acc[i][3] + bo;
        if (MODE==1) {
            const float4 pv = *(const float4*)&p1[((size_t)dir*512 + brow)*1024 + bn0 + tn];
            xi += pv.x; xf += pv.y; xg += pv.z; xo += pv.w;
        }
        float ig = 1.f/(1.f+expf(-xi));
        float fg = 1.f/(1.f+expf(-xf));
        float gg = tanhf(xg);
        float og = 1.f/(1.f+expf(-xo));
        size_t ci = (size_t)brow*1024 + hseg + jh;
        float cn = fg*c_st[ci] + ig*gg;
        float hn = og*tanhf(cn);
        c_st[ci]  = cn;
        h_out[ci] = hn;
        if (MODE==0) seqout[((size_t)t_eff*B + brow)*512 + dir*256 + jh] = hn;
    }
}

// ===========================================================================
// P1 precompute GEMM (round-2 validated, verbatim).
// ===========================================================================
__global__ __launch_bounds__(128)
void gemm_p1(const float* __restrict__ Wih, const float* __restrict__ hs0,
             float* __restrict__ p1out, int s0)
{
    constexpr int NK = 512/16;
    const int dir = blockIdx.z;

    __shared__ float As[16][64];
    __shared__ float Bs[16][64];

    const int tid = threadIdx.x;
    const int bm0 = blockIdx.x*64;
    const int bn0 = blockIdx.y*64;

    const int la_m  = tid >> 1;
    const int la_k  = (tid & 1) << 3;
    const int a_row = bm0 + la_m;

    const int srel  = blockIdx.x >> 3;
    const int sabs  = s0 + srel;
    const int t_eff = dir ? (S_IN-1-sabs) : sabs;
    const int a_b   = a_row & 511;

    const int n_g = bn0 + la_m;
    const int b_j = (n_g & 3)*256 + (n_g >> 2);

    const float* Wih_d = Wih + (size_t)dir*1024*512;

    const int tm = (tid >> 3) << 2;
    const int tn = (tid & 7) << 3;

    float acc[4][8] = {};

    auto loadA = [&](int kt, int q) -> float4 {
        int k = kt*16 + la_k + q*4;
        return *(const float4*)&hs0[((size_t)t_eff*B + a_b)*512 + k];
    };
    auto loadB = [&](int kt, int q) -> float4 {
        int k = kt*16 + la_k + q*4;
        return *(const float4*)&Wih_d[(size_t)b_j*512 + k];
    };

    float4 aR0 = loadA(0,0), aR1 = loadA(0,1);
    float4 bR0 = loadB(0,0), bR1 = loadB(0,1);
    for (int kt=0; kt<NK; ++kt) {
        __syncthreads();
        As[la_k+0][la_m]=aR0.x; As[la_k+1][la_m]=aR0.y; As[la_k+2][la_m]=aR0.z; As[la_k+3][la_m]=aR0.w;
        As[la_k+4][la_m]=aR1.x; As[la_k+5][la_m]=aR1.y; As[la_k+6][la_m]=aR1.z; As[la_k+7][la_m]=aR1.w;
        Bs[la_k+0][la_m]=bR0.x; Bs[la_k+1][la_m]=bR0.y; Bs[la_k+2][la_m]=bR0.z; Bs[la_k+3][la_m]=bR0.w;
        Bs[la_k+4][la_m]=bR1.x; Bs[la_k+5][la_m]=bR1.y; Bs[la_k+6][la_m]=bR1.z; Bs[la_k+7][la_m]=bR1.w;
        __syncthreads();
        if (kt+1 < NK) {
            aR0 = loadA(kt+1,0); aR1 = loadA(kt+1,1);
            bR0 = loadB(kt+1,0); bR1 = loadB(kt+1,1);
        }
        #pragma unroll
        for (int k=0;k<16;k++){
            const float4 a  = *(const float4*)&As[k][tm];
            const float4 b0 = *(const float4*)&Bs[k][tn];
            const float4 b1 = *(const float4*)&Bs[k][tn+4];
            acc[0][0]+=a.x*b0.x; acc[0][1]+=a.x*b0.y; acc[0][2]+=a.x*b0.z; acc[0][3]+=a.x*b0.w;
            acc[0][4]+=a.x*b1.x; acc[0][5]+=a.x*b1.y; acc[0][6]+=a.x*b1.z; acc[0][7]+=a.x*b1.w;
            acc[1][0]+=a.y*b0.x; acc[1][1]+=a.y*b0.y; acc[1][2]+=a.y*b0.z; acc[1][3]+=a.y*b0.w;
            acc[1][4]+=a.y*b1.x; acc[1][5]+=a.y*b1.y; acc[1][6]+=a.y*b1.z; acc[1][7]+=a.y*b1.w;
            acc[2][0]+=a.z*b0.x; acc[2][1]+=a.z*b0.y; acc[2][2]+=a.z*b0.z; acc[2][3]+=a.z*b0.w;
            acc[2][4]+=a.z*b1.x; acc[2][5]+=a.z*b1.y; acc[2][6]+=a.z*b1.z; acc[2][7]+=a.z*b1.w;
            acc[3][0]+=a.w*b0.x; acc[3][1]+=a.w*b0.y; acc[3][2]+=a.w*b0.z; acc[3][3]+=a.w*b0.w;
            acc[3][4]+=a.w*b1.x; acc[3][5]+=a.w*b1.y; acc[3][6]+=a.w*b1.z; acc[3][7]+=a.w*b1.w;
        }
    }

    #pragma unroll
    for (int i=0;i<4;i++){
        const int r = bm0 + tm + i;
        size_t base = ((size_t)(srel*2 + dir)*512 + (r & 511))*1024 + bn0 + tn;
        *(float4*)&p1out[base]   = *(float4*)&acc[i][0];
        *(float4*)&p1out[base+4] = *(float4*)&acc[i][4];
    }
}

// ===========================================================================
// Manual grid barrier (round-4 validated, verbatim).
// ===========================================================================
__device__ __forceinline__ void grid_bar(unsigned* cnt, unsigned target)
{
    __syncthreads();
    if (threadIdx.x == 0) {
        __threadfence();
        atomicAdd(cnt, 1u);
        while (__hip_atomic_load(cnt, __ATOMIC_ACQUIRE, __HIP_MEMORY_SCOPE_AGENT) < target) {
            __builtin_amdgcn_s_sleep(2);
        }
        __threadfence();
    }
    __syncthreads();
}

// inlined 4-way FMA helper (macro version had a token-substitution hazard)
__device__ __forceinline__ void fma4(float* ac, float s, float4 v)
{
    ac[0] += s*v.x; ac[1] += s*v.y; ac[2] += s*v.z; ac[3] += s*v.w;
}

// ===========================================================================
// Persistent decoder, W-in-LDS, 256 blocks x 1024 thr (16 waves/CU, 4/SIMD).
// Block owns 16 gate-cols (4 hidden units); W slice 16x1088 = 69.6 KB in LDS.
// Thread micro-tile: 1 row x 8 gate-cols (2 hidden units) -> per kk:
// 1 scalar A-read (lane-consecutive, conflict-free) + 2 broadcast W float4
// + 8 FMA. A staged per 16-k slice in As[16][512].
// Proj math = round-4 validated; barriers all wave-uniform at top level.
// ===========================================================================
__global__ __launch_bounds__(1024)
void dec_persist(const float* __restrict__ Wih, const float* __restrict__ Whh,
                 const float* __restrict__ bias, const int* __restrict__ tok,
                 const float* __restrict__ emb, const float* __restrict__ pW,
                 const float* __restrict__ pb, float* __restrict__ h0b,
                 float* __restrict__ h1b, float* __restrict__ c_st,
                 unsigned* __restrict__ bar, float* __restrict__ dout)
{
    extern __shared__ float smem[];
    float* Ws = smem;              // [1088][16]  69632 B
    float* As = smem + 17408;      // [16][512]   32768 B
    float* cs = smem + 25600;      // [2][1024]    8192 B
    float* ls = smem + 27648;      // [2][128]      512 B

    const int b = blockIdx.x, tid = threadIdx.x;
    const int bn0 = b*16;

    // ---- one-time W preload into LDS (gate-interleaved gather) ----
    {
        const int col = tid >> 6;                 // 16 cols, 64 threads each
        const int n_g = bn0 + col;
        const int wrow = (n_g & 3)*1024 + (n_g >> 2);
        for (int k0 = (tid & 63)*4; k0 < 1088; k0 += 256) {
            float4 v;
            if (k0 < 64) v = *(const float4*)&Wih[(size_t)wrow*64 + k0];
            else         v = *(const float4*)&Whh[(size_t)wrow*1024 + (k0-64)];
            Ws[(k0+0)*16 + col] = v.x;
            Ws[(k0+1)*16 + col] = v.y;
            Ws[(k0+2)*16 + col] = v.z;
            Ws[(k0+3)*16 + col] = v.w;
        }
    }
    __syncthreads();

    const int m   = tid & 511;              // compute row (1 per thread)
    const int tn  = (tid >> 9) << 3;        // 8 gate-cols = 2 hidden units
    const int jh  = (bn0 + tn) >> 2;
    const float bi0 = bias[jh],   bf0 = bias[1024+jh],   bg0 = bias[2048+jh],   bo0 = bias[3072+jh];
    const float bi1 = bias[jh+1], bf1 = bias[1024+jh+1], bg1 = bias[2048+jh+1], bo1 = bias[3072+jh+1];
    const int sm = tid >> 1, sq = tid & 1;  // staging row, k-half (8 k each)

    for (int t = 0; t < T_DEC; ++t) {
        const float* h_in  = (t & 1) ? h1b : h0b;
        float*       h_out = (t & 1) ? h0b : h1b;
        const int tok_s = tok[sm*S_OUT + t];

        auto ldrow = [&](int k) -> float4 {
            if (k < 64) return *(const float4*)&emb[(size_t)tok_s*64 + k];
            return *(const float4*)&h_in[(size_t)sm*1024 + (k-64)];
        };

        float4 pre0 = ldrow(sq*8);
        float4 pre1 = ldrow(sq*8 + 4);
        float acc[8] = {};

        for (int kt = 0; kt < 68; ++kt) {
            __syncthreads();
            {
                const int kq = sq*8;
                As[(kq+0)*512 + sm] = pre0.x;
                As[(kq+1)*512 + sm] = pre0.y;
                As[(kq+2)*512 + sm] = pre0.z;
                As[(kq+3)*512 + sm] = pre0.w;
                As[(kq+4)*512 + sm] = pre1.x;
                As[(kq+5)*512 + sm] = pre1.y;
                As[(kq+6)*512 + sm] = pre1.z;
                As[(kq+7)*512 + sm] = pre1.w;
            }
            __syncthreads();
            if (kt+1 < 68) {
                const int kb = (kt+1)*16 + sq*8;
                pre0 = ldrow(kb);
                pre1 = ldrow(kb + 4);
            }
            const int kg = kt*16;
            #pragma unroll
            for (int kk=0;kk<16;kk++){
                const float4 w0 = *(const float4*)&Ws[(kg+kk)*16 + tn];
                const float4 w1 = *(const float4*)&Ws[(kg+kk)*16 + tn + 4];
                const float a  = As[kk*512 + m];
                fma4(acc+0, a, w0);
                fma4(acc+4, a, w1);
            }
        }

        // ---- LSTM epilogue: 1 row x 2 hidden units ----
        {
            float xi=acc[0]+bi0, xf=acc[1]+bf0, xg=acc[2]+bg0, xo=acc[3]+bo0;
            float ig=1.f/(1.f+expf(-xi)), fg=1.f/(1.f+expf(-xf));
            float gg=tanhf(xg), og=1.f/(1.f+expf(-xo));
            const size_t ci=(size_t)m*1024 + jh;
            const float cn=fg*c_st[ci]+ig*gg, hn=og*tanhf(cn);
            c_st[ci]=cn; h_out[ci]=hn;
        }
        {
            float xi=acc[4]+bi1, xf=acc[5]+bf1, xg=acc[6]+bg1, xo=acc[7]+bo1;
            float ig=1.f/(1.f+expf(-xi)), fg=1.f/(1.f+expf(-xf));
            float gg=tanhf(xg), og=1.f/(1.f+expf(-xo));
            const size_t ci=(size_t)m*1024 + jh + 1;
            const float cn=fg*c_st[ci]+ig*gg, hn=og*tanhf(cn);
            c_st[ci]=cn; h_out[ci]=hn;
        }

        grid_bar(bar, (unsigned)(2*t+1) * 256u);

        // ---- fused projection on cell state, rows 2b, 2b+1 (round-4 math) ----
        *(float2*)&cs[tid*2] =
            *(const float2*)&c_st[(size_t)(2*b + (tid>>9))*1024 + (tid&511)*2];
        __syncthreads();
        if (tid < 256) {
            const int pr = tid >> 7, pc = tid & 127;
            float a0 = 0.f;
            for (int k=0;k<1024;k+=4){
                const float4 w  = *(const float4*)&pW[(size_t)pc*1024 + k];
                const float4 c0 = *(const float4*)&cs[pr*1024 + k];
                a0 += w.x*c0.x + w.y*c0.y + w.z*c0.z + w.w*c0.w;
            }
            ls[pr*128 + pc] = a0 + pb[pc];
        }
        __syncthreads();
        if (tid < 128) {
            const int r = tid >> 6, lane = tid & 63;
            const int gb = 2*b + r;
            const float v0 = ls[r*128 + lane], v1 = ls[r*128 + lane + 64];
            float mv; int mi;
            if (v1 > v0){ mv=v1; mi=lane+64; } else { mv=v0; mi=lane; }
            #pragma unroll
            for (int o=32;o>=1;o>>=1){
                const float ov = __shfl_xor(mv, o);
                const int   oi = __shfl_xor(mi, o);
                if (ov > mv || (ov == mv && oi < mi)){ mv=ov; mi=oi; }
            }
            float e = expf(v0-mv) + expf(v1-mv);
            #pragma unroll
            for (int o=32;o>=1;o>>=1) e += __shfl_xor(e, o);
            if (lane == 0){
                const int tnx = tok[gb*S_OUT + t + 1];
                const float logp = ls[r*128 + tnx] - mv - logf(e);
                const float cn = ((t==0)?0.f:dout[T_DEC*B + gb]) + logp;
                dout[T_DEC*B + gb] = cn;
                dout[t*B + gb] = (float)mi;
            }
        }

        grid_bar(bar, (unsigned)(2*t+2) * 256u);
    }
}

__global__ void zero_kernel(float* __restrict__ p, int n4){
    int i = blockIdx.x*blockDim.x + threadIdx.x;
    if (i < n4) *(float4*)&p[i*4] = float4{0.f,0.f,0.f,0.f};
}

extern "C" void kernel_launch(void* const* d_in, const int* in_sizes, int n_in,
                              void* d_out, int out_size, void* d_ws, size_t ws_size,
                              hipStream_t stream)
{
    const int*   input_tokens  = (const int*)d_in[0];
    const int*   output_tokens = (const int*)d_in[1];
    const float* in_emb  = (const float*)d_in[2];
    const float* eWih0   = (const float*)d_in[3];
    const float* eWhh0   = (const float*)d_in[4];
    const float* eb0     = (const float*)d_in[5];
    const float* eWih1   = (const float*)d_in[6];
    const float* eWhh1   = (const float*)d_in[7];
    const float* eb1     = (const float*)d_in[8];
    const float* out_emb = (const float*)d_in[9];
    const float* dWih    = (const float*)d_in[10];
    const float* dWhh    = (const float*)d_in[11];
    const float* db      = (const float*)d_in[12];
    const float* pW      = (const float*)d_in[13];
    const float* pb      = (const float*)d_in[14];

    size_t ws_fl = ws_size / 4;
    if (ws_fl < (size_t)O_P1) return;

    int CH = 0;
    if      (ws_fl >= (size_t)O_P1 + 16u*1048576u) CH = 16;
    else if (ws_fl >= (size_t)O_P1 +  8u*1048576u) CH = 8;
    else if (ws_fl >= (size_t)O_P1 +  4u*1048576u) CH = 4;
    else if (ws_fl >= (size_t)O_P1 +  2u*1048576u) CH = 2;

    float* ws   = (float*)d_ws;
    float* dout = (float*)d_out;

    float* h[2]   = { ws + O_H0, ws + O_H1 };
    float* c      = ws + O_C;
    unsigned* bar = (unsigned*)(ws + O_BAR);
    float* hs0    = ws + O_HS0;
    float* p1     = ws + O_P1;

    // zero h0,h1,c,bar
    zero_kernel<<<(O_HS0/4 + 255)/256, 256, 0, stream>>>(ws, O_HS0/4);

    // ---- encoder layer 0 (round-2 validated path) ----
    for (int t=0;t<S_IN;t++)
        enc_step<0><<<dim3(8,16,2),256,0,stream>>>(eWih0, eWhh0, eb0,
            input_tokens, in_emb, nullptr, h[t&1], h[(t+1)&1], c, hs0, nullptr, t);

    // ---- encoder layer 1 (round-2 validated path) ----
    if (CH) {
        for (int s0=0; s0<S_IN; s0+=CH) {
            gemm_p1<<<dim3(CH*8,16,2),128,0,stream>>>(eWih1, hs0, p1, s0);
            for (int s=s0; s<s0+CH; ++s)
                enc_step<1><<<dim3(8,16,2),256,0,stream>>>(eWih1, eWhh1, eb1,
                    nullptr, nullptr, nullptr, h[s&1], h[(s+1)&1], c, nullptr,
                    p1 + (size_t)(s-s0)*2*512*1024, s);
        }
    } else {
        for (int t=0;t<S_IN;t++)
            enc_step<2><<<dim3(8,16,2),256,0,stream>>>(eWih1, eWhh1, eb1,
                nullptr, nullptr, hs0, h[t&1], h[(t+1)&1], c, nullptr, nullptr, t);
    }

    // ---- persistent decoder: W pinned in LDS, 16 waves/CU ----
    dec_persist<<<256, 1024, 111616, stream>>>(dWih, dWhh, db, output_tokens,
                                               out_emb, pW, pb, h[0], h[1], c,
                                               bar, dout);
}

// Round 8
// 17056.302 us; speedup vs baseline: 1.9596x; 1.3645x over previous
//
#include <hip/hip_runtime.h>
#include <math.h>

#define B 512
#define S_IN 128
#define S_OUT 64
#define T_DEC 63

// ---- workspace layout (floats); fits the proven ws floor of 140.5 MB ----
#define O_H0   0
#define O_H1   524288
#define O_C    1048576
#define O_BAR  1572864                  // 4 floats reserved (barrier counter)
#define O_HS0  1572868                  // hs0: 128*512*512 = 33,554,432
#define O_P1   (O_HS0 + 33554432)      // 35,127,300 floats = 140.509 MB
// decoder-phase aliases inside the (dead-after-encoder) hs0 region:
#define D_HT0  O_HS0
#define D_HT1  (O_HS0 + 524288)
#define D_CT0  (O_HS0 + 1048576)
#define D_CT1  (O_HS0 + 1572864)
#define D_PWT  (O_HS0 + 2097152)       // pwt: 1024*128

// ===========================================================================
// Encoder step (256 thr, 64x64 tile, 4x4 micro) — round-2 validated, verbatim.
// ===========================================================================
template<int MODE>
__global__ __launch_bounds__(256)
void enc_step(const float* __restrict__ Wih, const float* __restrict__ Whh,
              const float* __restrict__ bias, const int* __restrict__ tok,
              const float* __restrict__ emb, const float* __restrict__ seqin,
              const float* __restrict__ h_in, float* __restrict__ h_out,
              float* __restrict__ c_st, float* __restrict__ seqout,
              const float* __restrict__ p1, int t)
{
    constexpr int KE = (MODE==0) ? 64 : (MODE==2 ? 512 : 0);
    constexpr int K  = KE + 256;
    constexpr int NK = K/16;

    const int dir   = blockIdx.z;
    const int t_eff = dir ? (S_IN-1-t) : t;
    const int hseg  = (MODE==0) ? dir*256 : 512 + dir*256;

    const float* Wih_d = Wih + (size_t)dir*1024*KE;
    const float* Whh_d = Whh + (size_t)dir*1024*256;
    const float* b_d   = bias + dir*1024;

    __shared__ float As[16][64];
    __shared__ float Bs[16][64];

    const int tid = threadIdx.x;
    const int bm0 = blockIdx.x*64;
    const int bn0 = blockIdx.y*64;

    const int la_m  = tid >> 2;
    const int la_k  = (tid & 3) << 2;
    const int a_row = bm0 + la_m;

    const int lb_n = tid >> 2;
    const int lb_k = (tid & 3) << 2;
    const int n_g  = bn0 + lb_n;
    const int b_j  = (n_g & 3)*256 + (n_g >> 2);

    int tokidx = 0;
    if (MODE==0) tokidx = tok[t_eff*B + a_row];

    const int tm = (tid >> 4) << 2;
    const int tn = (tid & 15) << 2;

    float acc[4][4] = {};

    auto loadA = [&](int kt) -> float4 {
        int k = kt*16 + la_k;
        if (MODE==0) {
            if (k < 64) return *(const float4*)&emb[(size_t)tokidx*64 + k];
            return *(const float4*)&h_in[(size_t)a_row*1024 + hseg + (k-64)];
        } else if (MODE==2) {
            if (k < 512) return *(const float4*)&seqin[((size_t)t_eff*B + a_row)*512 + k];
            return *(const float4*)&h_in[(size_t)a_row*1024 + hseg + (k-512)];
        } else {
            return *(const float4*)&h_in[(size_t)a_row*1024 + hseg + k];
        }
    };
    auto loadB = [&](int kt) -> float4 {
        int k = kt*16 + lb_k;
        if (KE && k < KE) return *(const float4*)&Wih_d[(size_t)b_j*KE + k];
        return *(const float4*)&Whh_d[(size_t)b_j*256 + (k-KE)];
    };

    float4 aR = loadA(0), bR = loadB(0);
    for (int kt=0; kt<NK; ++kt) {
        __syncthreads();
        As[la_k+0][la_m]=aR.x; As[la_k+1][la_m]=aR.y; As[la_k+2][la_m]=aR.z; As[la_k+3][la_m]=aR.w;
        Bs[lb_k+0][lb_n]=bR.x; Bs[lb_k+1][lb_n]=bR.y; Bs[lb_k+2][lb_n]=bR.z; Bs[lb_k+3][lb_n]=bR.w;
        __syncthreads();
        if (kt+1 < NK) { aR = loadA(kt+1); bR = loadB(kt+1); }
        #pragma unroll
        for (int k=0;k<16;k++){
            const float4 a = *(const float4*)&As[k][tm];
            const float4 b = *(const float4*)&Bs[k][tn];
            acc[0][0]+=a.x*b.x; acc[0][1]+=a.x*b.y; acc[0][2]+=a.x*b.z; acc[0][3]+=a.x*b.w;
            acc[1][0]+=a.y*b.x; acc[1][1]+=a.y*b.y; acc[1][2]+=a.y*b.z; acc[1][3]+=a.y*b.w;
            acc[2][0]+=a.z*b.x; acc[2][1]+=a.z*b.y; acc[2][2]+=a.z*b.z; acc[2][3]+=a.z*b.w;
            acc[3][0]+=a.w*b.x; acc[3][1]+=a.w*b.y; acc[3][2]+=a.w*b.z; acc[3][3]+=a.w*b.w;
        }
    }

    const int jh = (bn0 + tn) >> 2;
    const float bi = b_d[0*256 + jh];
    const float bf = b_d[1*256 + jh];
    const float bg = b_d[2*256 + jh];
    const float bo = b_d[3*256 + jh];
    #pragma unroll
    for (int i=0;i<4;i++){
        const int brow = bm0 + tm + i;
        float xi = acc[i][0] + bi;
        float xf = acc[i][1] + bf;
        float xg = acc[i][2] + bg;
        float xo = acc[i][3] + bo;
        if (MODE==1) {
            const float4 pv = *(const float4*)&p1[((size_t)dir*512 + brow)*1024 + bn0 + tn];
            xi += pv.x; xf += pv.y; xg += pv.z; xo += pv.w;
        }
        float ig = 1.f/(1.f+expf(-xi));
        float fg = 1.f/(1.f+expf(-xf));
        float gg = tanhf(xg);
        float og = 1.f/(1.f+expf(-xo));
        size_t ci = (size_t)brow*1024 + hseg + jh;
        float cn = fg*c_st[ci] + ig*gg;
        float hn = og*tanhf(cn);
        c_st[ci]  = cn;
        h_out[ci] = hn;
        if (MODE==0) seqout[((size_t)t_eff*B + brow)*512 + dir*256 + jh] = hn;
    }
}

// ===========================================================================
// P1 precompute GEMM (round-2 validated, verbatim).
// ===========================================================================
__global__ __launch_bounds__(128)
void gemm_p1(const float* __restrict__ Wih, const float* __restrict__ hs0,
             float* __restrict__ p1out, int s0)
{
    constexpr int NK = 512/16;
    const int dir = blockIdx.z;

    __shared__ float As[16][64];
    __shared__ float Bs[16][64];

    const int tid = threadIdx.x;
    const int bm0 = blockIdx.x*64;
    const int bn0 = blockIdx.y*64;

    const int la_m  = tid >> 1;
    const int la_k  = (tid & 1) << 3;
    const int a_row = bm0 + la_m;

    const int srel  = blockIdx.x >> 3;
    const int sabs  = s0 + srel;
    const int t_eff = dir ? (S_IN-1-sabs) : sabs;
    const int a_b   = a_row & 511;

    const int n_g = bn0 + la_m;
    const int b_j = (n_g & 3)*256 + (n_g >> 2);

    const float* Wih_d = Wih + (size_t)dir*1024*512;

    const int tm = (tid >> 3) << 2;
    const int tn = (tid & 7) << 3;

    float acc[4][8] = {};

    auto loadA = [&](int kt, int q) -> float4 {
        int k = kt*16 + la_k + q*4;
        return *(const float4*)&hs0[((size_t)t_eff*B + a_b)*512 + k];
    };
    auto loadB = [&](int kt, int q) -> float4 {
        int k = kt*16 + la_k + q*4;
        return *(const float4*)&Wih_d[(size_t)b_j*512 + k];
    };

    float4 aR0 = loadA(0,0), aR1 = loadA(0,1);
    float4 bR0 = loadB(0,0), bR1 = loadB(0,1);
    for (int kt=0; kt<NK; ++kt) {
        __syncthreads();
        As[la_k+0][la_m]=aR0.x; As[la_k+1][la_m]=aR0.y; As[la_k+2][la_m]=aR0.z; As[la_k+3][la_m]=aR0.w;
        As[la_k+4][la_m]=aR1.x; As[la_k+5][la_m]=aR1.y; As[la_k+6][la_m]=aR1.z; As[la_k+7][la_m]=aR1.w;
        Bs[la_k+0][la_m]=bR0.x; Bs[la_k+1][la_m]=bR0.y; Bs[la_k+2][la_m]=bR0.z; Bs[la_k+3][la_m]=bR0.w;
        Bs[la_k+4][la_m]=bR1.x; Bs[la_k+5][la_m]=bR1.y; Bs[la_k+6][la_m]=bR1.z; Bs[la_k+7][la_m]=bR1.w;
        __syncthreads();
        if (kt+1 < NK) {
            aR0 = loadA(kt+1,0); aR1 = loadA(kt+1,1);
            bR0 = loadB(kt+1,0); bR1 = loadB(kt+1,1);
        }
        #pragma unroll
        for (int k=0;k<16;k++){
            const float4 a  = *(const float4*)&As[k][tm];
            const float4 b0 = *(const float4*)&Bs[k][tn];
            const float4 b1 = *(const float4*)&Bs[k][tn+4];
            acc[0][0]+=a.x*b0.x; acc[0][1]+=a.x*b0.y; acc[0][2]+=a.x*b0.z; acc[0][3]+=a.x*b0.w;
            acc[0][4]+=a.x*b1.x; acc[0][5]+=a.x*b1.y; acc[0][6]+=a.x*b1.z; acc[0][7]+=a.x*b1.w;
            acc[1][0]+=a.y*b0.x; acc[1][1]+=a.y*b0.y; acc[1][2]+=a.y*b0.z; acc[1][3]+=a.y*b0.w;
            acc[1][4]+=a.y*b1.x; acc[1][5]+=a.y*b1.y; acc[1][6]+=a.y*b1.z; acc[1][7]+=a.y*b1.w;
            acc[2][0]+=a.z*b0.x; acc[2][1]+=a.z*b0.y; acc[2][2]+=a.z*b0.z; acc[2][3]+=a.z*b0.w;
            acc[2][4]+=a.z*b1.x; acc[2][5]+=a.z*b1.y; acc[2][6]+=a.z*b1.z; acc[2][7]+=a.z*b1.w;
            acc[3][0]+=a.w*b0.x; acc[3][1]+=a.w*b0.y; acc[3][2]+=a.w*b0.z; acc[3][3]+=a.w*b0.w;
            acc[3][4]+=a.w*b1.x; acc[3][5]+=a.w*b1.y; acc[3][6]+=a.w*b1.z; acc[3][7]+=a.w*b1.w;
        }
    }

    #pragma unroll
    for (int i=0;i<4;i++){
        const int r = bm0 + tm + i;
        size_t base = ((size_t)(srel*2 + dir)*512 + (r & 511))*1024 + bn0 + tn;
        *(float4*)&p1out[base]   = *(float4*)&acc[i][0];
        *(float4*)&p1out[base+4] = *(float4*)&acc[i][4];
    }
}

// ===========================================================================
// Manual grid barrier (round-4 validated, verbatim).
// ===========================================================================
__device__ __forceinline__ void grid_bar(unsigned* cnt, unsigned target)
{
    __syncthreads();
    if (threadIdx.x == 0) {
        __threadfence();
        atomicAdd(cnt, 1u);
        while (__hip_atomic_load(cnt, __ATOMIC_ACQUIRE, __HIP_MEMORY_SCOPE_AGENT) < target) {
            __builtin_amdgcn_s_sleep(2);
        }
        __threadfence();
    }
    __syncthreads();
}

__device__ __forceinline__ void fma4(float* ac, float s, float4 v)
{
    ac[0] += s*v.x; ac[1] += s*v.y; ac[2] += s*v.z; ac[3] += s*v.w;
}

// ===========================================================================
// Prep: transpose final encoder state into [unit][row] layout + pW -> pwt.
// ===========================================================================
__global__ void prep_kernel(const float* __restrict__ h0, const float* __restrict__ c0,
                            const float* __restrict__ pW, float* __restrict__ hT0,
                            float* __restrict__ cT1, float* __restrict__ pwt)
{
    const int i = blockIdx.x*blockDim.x + threadIdx.x;
    if (i < 524288) {
        const int u = i >> 9, r = i & 511;
        hT0[i] = h0[(size_t)r*1024 + u];
        cT1[i] = c0[(size_t)r*1024 + u];
    }
    if (i < 131072) {
        const int k = i >> 7, v = i & 127;
        pwt[i] = pW[(size_t)v*1024 + k];
    }
}

// ===========================================================================
// Persistent decoder v3: W-in-LDS (69.6 KB) + TRANSPOSED state hT/cT[unit][row]
// (double-buffered) + double-buffered As (1 block-barrier/kt) + 1 grid
// barrier/step + k-split proj on transposed pwt (coalesced streaming).
// 256 blocks x 1024 thr. All global writes are full-line contiguous.
// ===========================================================================
__global__ __launch_bounds__(1024)
void dec_persist(const float* __restrict__ Wih, const float* __restrict__ Whh,
                 const float* __restrict__ bias, const int* __restrict__ tok,
                 const float* __restrict__ emb, const float* __restrict__ pwt,
                 const float* __restrict__ pb, float* __restrict__ hT0,
                 float* __restrict__ hT1, float* __restrict__ cT0,
                 float* __restrict__ cT1, unsigned* __restrict__ bar,
                 float* __restrict__ dout)
{
    extern __shared__ float smem[];
    float* Ws = smem;                    // [1088][16]          69632 B
    float* As = smem + 17408;            // 2 x [16][512]       65536 B
    // proj scratch aliased into As buffer 0 (sequentially safe):
    float* cs0  = As;                    // [1024]
    float* cs1  = As + 1024;             // [1024]
    float* part = As + 2048;             // [8][2][128]
    float* ls   = As + 4096;             // [2][128]

    const int b = blockIdx.x, tid = threadIdx.x;
    const int bn0 = b*16;

    // ---- one-time W preload into LDS (gate-interleaved gather) ----
    {
        const int col = tid >> 6;
        const int n_g = bn0 + col;
        const int wrow = (n_g & 3)*1024 + (n_g >> 2);
        for (int k0 = (tid & 63)*4; k0 < 1088; k0 += 256) {
            float4 v;
            if (k0 < 64) v = *(const float4*)&Wih[(size_t)wrow*64 + k0];
            else         v = *(const float4*)&Whh[(size_t)wrow*1024 + (k0-64)];
            Ws[(k0+0)*16 + col] = v.x;
            Ws[(k0+1)*16 + col] = v.y;
            Ws[(k0+2)*16 + col] = v.z;
            Ws[(k0+3)*16 + col] = v.w;
        }
    }
    __syncthreads();

    const int m   = tid & 511;             // GEMM row
    const int tn  = (tid >> 9) << 3;       // 8 gate-cols = 2 hidden units
    const int jh  = (bn0 + tn) >> 2;
    const float bi0 = bias[jh],   bf0 = bias[1024+jh],   bg0 = bias[2048+jh],   bo0 = bias[3072+jh];
    const float bi1 = bias[jh+1], bf1 = bias[1024+jh+1], bg1 = bias[2048+jh+1], bo1 = bias[3072+jh+1];
    const int sj  = tid >> 6;              // h-staging: k-within-slice (0..15)
    const int sr  = (tid & 63)*8;          // h-staging: 8-row chunk
    const int esm = tid >> 1, esq = tid & 1;  // emb-staging: row / k-half

    for (int t = 0; t < T_DEC; ++t) {
        const float* hT_in  = (t & 1) ? hT1 : hT0;
        float*       hT_out = (t & 1) ? hT0 : hT1;
        const float* cT_in  = (t & 1) ? cT0 : cT1;   // c_{t-1}
        float*       cT_out = (t & 1) ? cT1 : cT0;   // c_t (proj reads this)

        const int etok = tok[esm*S_OUT + t];

        // prologue: stage regs for kt=0 (emb slice)
        float4 pre0 = *(const float4*)&emb[(size_t)etok*64 + esq*8];
        float4 pre1 = *(const float4*)&emb[(size_t)etok*64 + esq*8 + 4];
        float acc[8] = {};

        for (int kt = 0; kt < 68; ++kt) {
            float* buf = As + (kt & 1)*8192;
            // write staged regs for this kt
            if (kt < 4) {
                const int j0 = esq*8;
                buf[(j0+0)*512+esm]=pre0.x; buf[(j0+1)*512+esm]=pre0.y;
                buf[(j0+2)*512+esm]=pre0.z; buf[(j0+3)*512+esm]=pre0.w;
                buf[(j0+4)*512+esm]=pre1.x; buf[(j0+5)*512+esm]=pre1.y;
                buf[(j0+6)*512+esm]=pre1.z; buf[(j0+7)*512+esm]=pre1.w;
            } else {
                *(float4*)&buf[sj*512 + sr]     = pre0;
                *(float4*)&buf[sj*512 + sr + 4] = pre1;
            }
            // stage next slice
            if (kt+1 < 68) {
                if (kt+1 < 4) {
                    pre0 = *(const float4*)&emb[(size_t)etok*64 + (kt+1)*16 + esq*8];
                    pre1 = *(const float4*)&emb[(size_t)etok*64 + (kt+1)*16 + esq*8 + 4];
                } else {
                    const float* src = &hT_in[(size_t)((kt+1)*16 - 64 + sj)*512 + sr];
                    pre0 = *(const float4*)&src[0];
                    pre1 = *(const float4*)&src[4];
                }
            }
            __syncthreads();
            const int kg = kt*16;
            #pragma unroll
            for (int kk=0;kk<16;kk++){
                const float4 w0 = *(const float4*)&Ws[(kg+kk)*16 + tn];
                const float4 w1 = *(const float4*)&Ws[(kg+kk)*16 + tn + 4];
                const float a  = buf[kk*512 + m];
                fma4(acc+0, a, w0);
                fma4(acc+4, a, w1);
            }
        }

        // ---- LSTM epilogue: transposed state, fully-coalesced writes ----
        {
            float xi=acc[0]+bi0, xf=acc[1]+bf0, xg=acc[2]+bg0, xo=acc[3]+bo0;
            float ig=1.f/(1.f+expf(-xi)), fg=1.f/(1.f+expf(-xf));
            float gg=tanhf(xg), og=1.f/(1.f+expf(-xo));
            const size_t ci = (size_t)jh*512 + m;
            const float cn = fg*cT_in[ci] + ig*gg, hn = og*tanhf(cn);
            cT_out[ci] = cn; hT_out[ci] = hn;
        }
        {
            float xi=acc[4]+bi1, xf=acc[5]+bf1, xg=acc[6]+bg1, xo=acc[7]+bo1;
            float ig=1.f/(1.f+expf(-xi)), fg=1.f/(1.f+expf(-xf));
            float gg=tanhf(xg), og=1.f/(1.f+expf(-xo));
            const size_t ci = (size_t)(jh+1)*512 + m;
            const float cn = fg*cT_in[ci] + ig*gg, hn = og*tanhf(cn);
            cT_out[ci] = cn; hT_out[ci] = hn;
        }

        grid_bar(bar, (unsigned)(t+1) * 256u);

        // ---- fused projection, rows 2b/2b+1, k-split across 16 waves ----
        {
            const float2 v = *(const float2*)&cT_out[(size_t)tid*512 + 2*b];
            cs0[tid] = v.x; cs1[tid] = v.y;
        }
        __syncthreads();
        {
            const int kgp = tid >> 7, pc = tid & 127;
            float a0 = 0.f, a1 = 0.f;
            const int k0 = kgp*128;
            #pragma unroll 4
            for (int ki=0; ki<128; ++ki){
                const float w = pwt[(size_t)(k0+ki)*128 + pc];
                a0 += w*cs0[k0+ki];
                a1 += w*cs1[k0+ki];
            }
            part[(kgp*2+0)*128 + pc] = a0;
            part[(kgp*2+1)*128 + pc] = a1;
        }
        __syncthreads();
        if (tid < 256) {
            const int pr = tid >> 7, pc = tid & 127;
            float s = pb[pc];
            #pragma unroll
            for (int kg2=0; kg2<8; ++kg2) s += part[(kg2*2+pr)*128 + pc];
            ls[pr*128 + pc] = s;
        }
        __syncthreads();
        if (tid < 128) {
            const int r = tid >> 6, lane = tid & 63;
            const int gb = 2*b + r;
            const float v0 = ls[r*128 + lane], v1 = ls[r*128 + lane + 64];
            float mv; int mi;
            if (v1 > v0){ mv=v1; mi=lane+64; } else { mv=v0; mi=lane; }
            #pragma unroll
            for (int o=32;o>=1;o>>=1){
                const float ov = __shfl_xor(mv, o);
                const int   oi = __shfl_xor(mi, o);
                if (ov > mv || (ov == mv && oi < mi)){ mv=ov; mi=oi; }
            }
            float e = expf(v0-mv) + expf(v1-mv);
            #pragma unroll
            for (int o=32;o>=1;o>>=1) e += __shfl_xor(e, o);
            if (lane == 0){
                const int tnx = tok[gb*S_OUT + t + 1];
                const float logp = ls[r*128 + tnx] - mv - logf(e);
                const float cn = ((t==0)?0.f:dout[T_DEC*B + gb]) + logp;
                dout[T_DEC*B + gb] = cn;
                dout[t*B + gb] = (float)mi;
            }
        }
        __syncthreads();   // protect As region (proj scratch) before next staging
    }
}

__global__ void zero_kernel(float* __restrict__ p, int n4){
    int i = blockIdx.x*blockDim.x + threadIdx.x;
    if (i < n4) *(float4*)&p[i*4] = float4{0.f,0.f,0.f,0.f};
}

extern "C" void kernel_launch(void* const* d_in, const int* in_sizes, int n_in,
                              void* d_out, int out_size, void* d_ws, size_t ws_size,
                              hipStream_t stream)
{
    const int*   input_tokens  = (const int*)d_in[0];
    const int*   output_tokens = (const int*)d_in[1];
    const float* in_emb  = (const float*)d_in[2];
    const float* eWih0   = (const float*)d_in[3];
    const float* eWhh0   = (const float*)d_in[4];
    const float* eb0     = (const float*)d_in[5];
    const float* eWih1   = (const float*)d_in[6];
    const float* eWhh1   = (const float*)d_in[7];
    const float* eb1     = (const float*)d_in[8];
    const float* out_emb = (const float*)d_in[9];
    const float* dWih    = (const float*)d_in[10];
    const float* dWhh    = (const float*)d_in[11];
    const float* db      = (const float*)d_in[12];
    const float* pW      = (const float*)d_in[13];
    const float* pb      = (const float*)d_in[14];

    size_t ws_fl = ws_size / 4;
    if (ws_fl < (size_t)O_P1) return;

    int CH = 0;
    if      (ws_fl >= (size_t)O_P1 + 16u*1048576u) CH = 16;
    else if (ws_fl >= (size_t)O_P1 +  8u*1048576u) CH = 8;
    else if (ws_fl >= (size_t)O_P1 +  4u*1048576u) CH = 4;
    else if (ws_fl >= (size_t)O_P1 +  2u*1048576u) CH = 2;

    float* ws   = (float*)d_ws;
    float* dout = (float*)d_out;

    float* h[2]   = { ws + O_H0, ws + O_H1 };
    float* c      = ws + O_C;
    unsigned* bar = (unsigned*)(ws + O_BAR);
    float* hs0    = ws + O_HS0;
    float* p1     = ws + O_P1;
    float* hT0    = ws + D_HT0;
    float* hT1    = ws + D_HT1;
    float* cT0    = ws + D_CT0;
    float* cT1    = ws + D_CT1;
    float* pwt    = ws + D_PWT;

    // zero h0,h1,c,bar
    zero_kernel<<<(O_HS0/4 + 255)/256, 256, 0, stream>>>(ws, O_HS0/4);

    // ---- encoder layer 0 (round-2 validated path) ----
    for (int t=0;t<S_IN;t++)
        enc_step<0><<<dim3(8,16,2),256,0,stream>>>(eWih0, eWhh0, eb0,
            input_tokens, in_emb, nullptr, h[t&1], h[(t+1)&1], c, hs0, nullptr, t);

    // ---- encoder layer 1 (round-2 validated path) ----
    if (CH) {
        for (int s0=0; s0<S_IN; s0+=CH) {
            gemm_p1<<<dim3(CH*8,16,2),128,0,stream>>>(eWih1, hs0, p1, s0);
            for (int s=s0; s<s0+CH; ++s)
                enc_step<1><<<dim3(8,16,2),256,0,stream>>>(eWih1, eWhh1, eb1,
                    nullptr, nullptr, nullptr, h[s&1], h[(s+1)&1], c, nullptr,
                    p1 + (size_t)(s-s0)*2*512*1024, s);
        }
    } else {
        for (int t=0;t<S_IN;t++)
            enc_step<2><<<dim3(8,16,2),256,0,stream>>>(eWih1, eWhh1, eb1,
                nullptr, nullptr, hs0, h[t&1], h[(t+1)&1], c, nullptr, nullptr, t);
    }

    // ---- prep: transpose state + pW (hs0 is dead from here on) ----
    prep_kernel<<<2048,256,0,stream>>>(h[0], c, pW, hT0, cT1, pwt);

    // ---- persistent decoder v3 ----
    dec_persist<<<256, 1024, 135168, stream>>>(dWih, dWhh, db, output_tokens,
                                               out_emb, pwt, pb, hT0, hT1,
                                               cT0, cT1, bar, dout);
}